// Round 10
// baseline (344.615 us; speedup 1.0000x reference)
//
#include <hip/hip_runtime.h>
#include <math.h>

// Shapes (fixed by the problem)
#define B_   4
#define N_   16384
#define M_   4096
#define C1_  128
#define C2_  256
#define H_   256
#define K1_  384   // C1 + C2

#define NC_  8           // three_nn chunks over M  (DO NOT CHANGE: selection
#define MC_  (M_ / NC_)  //  dynamics are part of the verified numerics)

typedef unsigned long long u64;
typedef __attribute__((ext_vector_type(8))) short bf16x8;   // 8 bf16 (4 VGPRs)
typedef __attribute__((ext_vector_type(4))) float f32x4;    // mfma acc

typedef const __attribute__((address_space(1))) unsigned int* gptr_t;
typedef __attribute__((address_space(3))) unsigned int* lptr_t;

__device__ __forceinline__ unsigned short f2bf(float x) {
  unsigned u = __float_as_uint(x);
  return (unsigned short)((u + 0x7FFFu + ((u >> 16) & 1u)) >> 16);  // RNE
}
__device__ __forceinline__ float bf2f(unsigned short u) {
  return __uint_as_float((unsigned)u << 16);
}

// BN scale/shift from raw sums — VERBATIM k_reduce_bn arithmetic.
__device__ __forceinline__ float2 bnparam(float s, float q, float gm, float bt) {
  const float inv = 1.0f / (float)(B_ * N_);
  float mean = s * inv;
  float var  = q * inv - mean * mean;
  float sc = gm / sqrtf(var + 1e-5f);
  return make_float2(sc, bt - mean * sc);
}

// fp32-pair branchless insert (merge phase only)
__device__ __forceinline__ void ins3(float cd, int ci,
                                     float& d1, int& i1,
                                     float& d2, int& i2,
                                     float& d3, int& i3) {
  bool p3 = cd < d3, p2 = cd < d2, p1 = cd < d1;
  float td = p1 ? d1 : cd; int ti = p1 ? i1 : ci;
  d1 = p1 ? cd : d1;       i1 = p1 ? ci : i1;
  float e3 = p2 ? d2 : cd; int e3i = p2 ? i2 : ci;
  d2 = p2 ? td : d2;       i2 = p2 ? ti : i2;
  d3 = p3 ? e3 : d3;       i3 = p3 ? e3i : i3;
}

// ---------------------------------------------------------------------------
// 1) k_front — flat grid fusing three independent jobs:
//      f in [0,4096)     : transpose known_feats -> kfT        (short, first)
//      f in [4096,4736)  : cast W1/W2 -> bf16 Wb               (short)
//      f in [4736,6784)  : three_nn partials                   (long, backfills)
//    Short memory-bound blocks dispatch first and drain while the VALU-bound
//    three_nn blocks fill the CUs -> pre-work runs ~free under three_nn.
//    three_nn decode g=f-4736: x=g&63, b=(g>>6)&3, ch=g>>8 == the verified
//    dim3(64,4,8) x-fastest mapping -> block->(j,b,ch) and wave composition
//    BYTE-IDENTICAL -> selection dynamics unchanged (R4-proven numerics).
// ---------------------------------------------------------------------------
__global__ __launch_bounds__(256) void k_front(const float* __restrict__ kf,
                                               float* __restrict__ kfT,
                                               const float* __restrict__ W1,
                                               const float* __restrict__ W2,
                                               unsigned short* __restrict__ Wb,
                                               const float* __restrict__ unknown,
                                               const float* __restrict__ known,
                                               float* __restrict__ part_d,
                                               int* __restrict__ part_i) {
  __shared__ __align__(16) char smem[8192];
  int f = blockIdx.x;
  int t = threadIdx.x;

  if (f < 4096) {              // ---- transpose kf [B,C2,M] -> kfT [B,M,C2]
    float (*tile)[33] = (float (*)[33])smem;
    int b  = f >> 10;
    int c0 = ((f >> 7) & 7) * 32;
    int i0 = (f & 127) * 32;
    int tx = t & 31, tyv = t >> 5;
    const float* src = kf + ((size_t)b * C2_ + c0) * M_ + i0;
    #pragma unroll
    for (int r = 0; r < 32; r += 8)
      tile[tyv + r][tx] = src[(size_t)(tyv + r) * M_ + tx];
    __syncthreads();
    float* dst = kfT + ((size_t)b * M_ + i0) * C2_ + c0;
    #pragma unroll
    for (int r = 0; r < 32; r += 8)
      dst[(size_t)(tyv + r) * C2_ + tx] = tile[tx][tyv + r];
    return;
  }
  if (f < 4736) {              // ---- wcast
    int i = (f - 4096) * 256 + t;
    int n1 = H_ * K1_, nt = n1 + H_ * H_;
    if (i < nt) Wb[i] = f2bf(i < n1 ? W1[i] : W2[i - n1]);
    return;
  }

  // ---- three_nn partials — BYTE-EXACT R4 body (DO NOT TOUCH) ----
  float4* sk = (float4*)smem;
  int g    = f - 4736;
  int b    = (g >> 6) & 3;
  int ch   = g >> 8;
  int base = ch * MC_;
  const float* kb = known + ((size_t)b * M_ + base) * 3;
  for (int i = t; i < MC_; i += 256) {
    float x = kb[3*i+0], y = kb[3*i+1], z = kb[3*i+2];
    sk[i] = make_float4(-2.0f*x, -2.0f*y, -2.0f*z, x*x + y*y + z*z);
  }
  __syncthreads();

  int j = (g & 63) * 256 + t;
  const float* up = unknown + ((size_t)b * N_ + j) * 3;
  float ux = up[0], uy = up[1], uz = up[2];
  float u2 = ux*ux + uy*uy + uz*uz;

  const float INF = __builtin_inff();
  float d1 = INF, d2 = INF, d3 = INF, t3 = INF;
  int   i1 = 0, i2 = 0, i3 = 0;
  #pragma unroll 4
  for (int i = 0; i < MC_; ++i) {
    float4 k = sk[i];
    float s = fmaf(k.x, ux, fmaf(k.y, uy, fmaf(k.z, uz, k.w)));  // k2 - 2*dot
    if (__any(s < t3)) {
      float d = u2 + s;
      int  gi = base + i;
      bool p3 = d < d3, p2 = d < d2, p1 = d < d1;
      int ni1 = p1 ? gi : i1;
      int ni2 = p1 ? i1 : (p2 ? gi : i2);
      int ni3 = p2 ? i2 : (p3 ? gi : i3);
      float nd1 = fminf(d, d1);
      float nd2 = __builtin_amdgcn_fmed3f(d, d1, d2);
      float nd3 = __builtin_amdgcn_fmed3f(d, d2, d3);
      d1 = nd1; d2 = nd2; d3 = nd3;
      i1 = ni1; i2 = ni2; i3 = ni3;
      t3 = d3 - u2;
    }
  }
  size_t o = ((size_t)(ch * B_ + b) * 3) * N_ + j;
  part_d[o] = d1; part_d[o + N_] = d2; part_d[o + 2*(size_t)N_] = d3;
  part_i[o] = i1; part_i[o + N_] = i2; part_i[o + 2*(size_t)N_] = i3;
}

// ---------------------------------------------------------------------------
// 2) pre2: fused {merge + three_interpolate} (y==4) and uf_t (y<4).
//    Bodies verbatim (bit-identical Xb1). The (x==0,y==4,b==0) block also
//    zeroes the layer-1 BN accumulators for this iteration.
// ---------------------------------------------------------------------------
__global__ __launch_bounds__(256) void k_pre2(const float* __restrict__ part_d,
                                              const int* __restrict__ part_i,
                                              const float* __restrict__ kfT,
                                              const float* __restrict__ uf,
                                              unsigned short* __restrict__ Xb1,
                                              float* __restrict__ acc1) {
  int b = blockIdx.z;
  if (blockIdx.y < 4) {
    // ---- uf_t: transpose+cast unknown_feats [B,C1,N] -> Xb1[b][j][256+c]
    __shared__ float tile[32][33];
    int j0 = blockIdx.x * 32;
    int c0 = blockIdx.y * 32;
    int tx = threadIdx.x & 31, ty = threadIdx.x >> 5;
    const float* src = uf + ((size_t)b * C1_ + c0) * N_ + j0;
    #pragma unroll
    for (int r = 0; r < 32; r += 8)
      tile[ty + r][tx] = src[(size_t)(ty + r) * N_ + tx];
    __syncthreads();
    unsigned short* dst = Xb1 + ((size_t)b * N_ + j0) * K1_ + C2_ + c0;
    #pragma unroll
    for (int r = 0; r < 32; r += 8)
      dst[(size_t)(ty + r) * K1_ + tx] = f2bf(tile[tx][ty + r]);
    return;
  }
  int t  = threadIdx.x;
  if (blockIdx.x == 0 && b == 0) {      // zero layer-1 BN accumulators
    acc1[t] = 0.0f; acc1[256 + t] = 0.0f;
  }
  // ---- merge (threads 0..31, one point each) + interp (all 256 threads)
  __shared__ float lw[32][3];
  __shared__ int   li[32][3];
  int j0 = blockIdx.x * 32;
  if (t < 32) {
    int j = j0 + t;
    size_t o0 = ((size_t)b * 3) * N_ + j;
    float d1 = part_d[o0], d2 = part_d[o0 + N_], d3 = part_d[o0 + 2*(size_t)N_];
    int   i1 = part_i[o0], i2 = part_i[o0 + N_], i3 = part_i[o0 + 2*(size_t)N_];
    #pragma unroll
    for (int c = 1; c < NC_; ++c) {
      size_t oc = ((size_t)(c * B_ + b) * 3) * N_ + j;
      #pragma unroll
      for (int k = 0; k < 3; ++k) {
        float cd = part_d[oc + (size_t)k * N_];
        int   ci = part_i[oc + (size_t)k * N_];
        ins3(cd, ci, d1, i1, d2, i2, d3, i3);
      }
    }
    float r1 = 1.0f / (d1 + 1e-8f);
    float r2 = 1.0f / (d2 + 1e-8f);
    float r3 = 1.0f / (d3 + 1e-8f);
    float s  = r1 + r2 + r3;
    li[t][0] = i1; li[t][1] = i2; li[t][2] = i3;
    lw[t][0] = r1 / s; lw[t][1] = r2 / s; lw[t][2] = r3 / s;
  }
  __syncthreads();
  const float* kb = kfT + (size_t)b * M_ * C2_;
  int c = t;
  for (int p = 0; p < 32; ++p) {
    int   i0 = li[p][0], i1 = li[p][1], i2 = li[p][2];
    float w0 = lw[p][0], w1 = lw[p][1], w2 = lw[p][2];
    float v = w0 * kb[(size_t)i0 * C2_ + c]
            + w1 * kb[(size_t)i1 * C2_ + c]
            + w2 * kb[(size_t)i2 * C2_ + c];
    Xb1[((size_t)b * N_ + j0 + p) * K1_ + c] = f2bf(v);
  }
}

// ---------------------------------------------------------------------------
// 3) bf16 MFMA GEMM, global_load_lds-staged (verified R9 structure).
//    Stats tail now atomicAdds the per-block channel sums into acc[0:256)
//    (sum) / acc[256:512) (sumsq). Atomic order wobbles BN stats by ulps --
//    smooth arithmetic, not selection dynamics (safe; R1-R3 lesson applies
//    only to the top-3 selection). Everything else byte-identical to R9.
// ---------------------------------------------------------------------------
template <int K, int OUTL>
__global__ __launch_bounds__(256) void k_gemm_mfma(const unsigned short* __restrict__ Wb,
                                                   const unsigned short* __restrict__ Xb,
                                                   float* __restrict__ outp,
                                                   float* __restrict__ acc) {
  __shared__ float sred[256];
  __shared__ unsigned short lA[4096];   // [128][32] bf16 = 8 KB
  __shared__ unsigned short lB[4096];
  int t = threadIdx.x;
  sred[t] = 0.0f;
  __syncthreads();

  int b  = blockIdx.z;
  int m0 = blockIdx.y * 128;
  int j0 = blockIdx.x * 128;
  int wid = t >> 6, lane = t & 63;
  int wr = wid >> 1, wc = wid & 1;
  int l15 = lane & 15, quad = lane >> 4;

  int srow = lane >> 2;
  int scol = (lane & 3) * 8;
  int c0 = wid * 2, c1 = wid * 2 + 1;
  const unsigned short* gA0 = Wb + (size_t)(m0 + c0*16 + srow) * K + scol;
  const unsigned short* gA1 = Wb + (size_t)(m0 + c1*16 + srow) * K + scol;
  const unsigned short* gB0 = Xb + ((size_t)b * N_ + j0 + c0*16 + srow) * K + scol;
  const unsigned short* gB1 = Xb + ((size_t)b * N_ + j0 + c1*16 + srow) * K + scol;
  unsigned short* sA0 = lA + c0 * 512;
  unsigned short* sA1 = lA + c1 * 512;
  unsigned short* sB0 = lB + c0 * 512;
  unsigned short* sB1 = lB + c1 * 512;

  const unsigned short* fA = lA + (64*wr + l15) * 32 + quad * 8;
  const unsigned short* fB = lB + (64*wc + l15) * 32 + quad * 8;

  f32x4 acc_r[4][4] = {};
  for (int kt = 0; kt < K; kt += 32) {
    __builtin_amdgcn_global_load_lds((gptr_t)(gA0 + kt), (lptr_t)sA0, 16, 0, 0);
    __builtin_amdgcn_global_load_lds((gptr_t)(gA1 + kt), (lptr_t)sA1, 16, 0, 0);
    __builtin_amdgcn_global_load_lds((gptr_t)(gB0 + kt), (lptr_t)sB0, 16, 0, 0);
    __builtin_amdgcn_global_load_lds((gptr_t)(gB1 + kt), (lptr_t)sB1, 16, 0, 0);
    __syncthreads();
    bf16x8 af[4], bfr[4];
    #pragma unroll
    for (int i = 0; i < 4; ++i)
      af[i] = *(const bf16x8*)(fA + i * 512);
    #pragma unroll
    for (int i = 0; i < 4; ++i)
      bfr[i] = *(const bf16x8*)(fB + i * 512);
    #pragma unroll
    for (int im = 0; im < 4; ++im)
      #pragma unroll
      for (int in = 0; in < 4; ++in)
        acc_r[im][in] = __builtin_amdgcn_mfma_f32_16x16x32_bf16(af[im], bfr[in], acc_r[im][in], 0, 0, 0);
    __syncthreads();
  }

  // --- BN statistics: shuffle-reduce over 16 n-lanes, combine in LDS ---
  #pragma unroll
  for (int im = 0; im < 4; ++im) {
    #pragma unroll
    for (int r = 0; r < 4; ++r) {
      float sv = 0.f, qv = 0.f;
      #pragma unroll
      for (int in = 0; in < 4; ++in) { float v = acc_r[im][in][r]; sv += v; qv += v * v; }
      #pragma unroll
      for (int off = 1; off < 16; off <<= 1) {
        sv += __shfl_xor(sv, off, 64);
        qv += __shfl_xor(qv, off, 64);
      }
      if (l15 == 0) {
        int ml = 64*wr + 16*im + 4*quad + r;
        atomicAdd(&sred[ml], sv);
        atomicAdd(&sred[128 + ml], qv);
      }
    }
  }
  __syncthreads();
  if (t < 128) {
    atomicAdd(&acc[m0 + t],       sred[t]);        // device-scope fp32 atomics
    atomicAdd(&acc[256 + m0 + t], sred[128 + t]);
  }

  // --- store ---
  if (OUTL == 0) {
    unsigned short* hp = (unsigned short*)outp;   // h bf16 [b][n][256]
    #pragma unroll
    for (int in = 0; in < 4; ++in) {
      size_t nrow = (size_t)b * N_ + j0 + 64*wc + 16*in + l15;
      unsigned short* p = hp + nrow * 256 + m0 + 64*wr + quad * 4;
      #pragma unroll
      for (int im = 0; im < 4; ++im) {
        ushort4 o;
        o.x = f2bf(acc_r[im][in][0]); o.y = f2bf(acc_r[im][in][1]);
        o.z = f2bf(acc_r[im][in][2]); o.w = f2bf(acc_r[im][in][3]);
        *(ushort4*)(p + 16 * im) = o;
      }
    }
  } else {
    #pragma unroll
    for (int im = 0; im < 4; ++im)
      #pragma unroll
      for (int r = 0; r < 4; ++r) {
        int m = m0 + 64*wr + 16*im + 4*quad + r;
        size_t base = ((size_t)b * 256 + m) * N_ + j0 + 64*wc + l15;
        #pragma unroll
        for (int in = 0; in < 4; ++in)
          outp[base + 16 * in] = acc_r[im][in][r];
      }
  }
}

// ---------------------------------------------------------------------------
// 4) bn1 + relu: h bf16 -> Xb2 bf16. BN params computed on the fly from the
//    raw atomic sums (formula verbatim == old reduce_bn -> same bits given
//    same sums). Block 0 zeroes the layer-2 accumulators for gemm2.
// ---------------------------------------------------------------------------
__global__ __launch_bounds__(256) void k_bn_relu_cast(const unsigned short* __restrict__ h,
                                                      const float* __restrict__ acc1,
                                                      const float* __restrict__ gamma,
                                                      const float* __restrict__ beta,
                                                      unsigned short* __restrict__ Xb2,
                                                      float* __restrict__ acc2) {
  int t = threadIdx.x;
  if (blockIdx.x == 0) { acc2[t] = 0.0f; acc2[256 + t] = 0.0f; }
  size_t e = (size_t)blockIdx.x * 256 + t;             // ushort4 index
  ushort4 v = ((const ushort4*)h)[e];
  int c0 = (int)((e & 63) << 2);
  float4 s4 = *(const float4*)(acc1 + c0);
  float4 q4 = *(const float4*)(acc1 + 256 + c0);
  float4 gm = *(const float4*)(gamma + c0);
  float4 bt = *(const float4*)(beta + c0);
  float2 p0 = bnparam(s4.x, q4.x, gm.x, bt.x);
  float2 p1 = bnparam(s4.y, q4.y, gm.y, bt.y);
  float2 p2 = bnparam(s4.z, q4.z, gm.z, bt.z);
  float2 p3 = bnparam(s4.w, q4.w, gm.w, bt.w);
  ushort4 o;
  o.x = f2bf(fmaxf(fmaf(p0.x, bf2f(v.x), p0.y), 0.0f));
  o.y = f2bf(fmaxf(fmaf(p1.x, bf2f(v.y), p1.y), 0.0f));
  o.z = f2bf(fmaxf(fmaf(p2.x, bf2f(v.z), p2.y), 0.0f));
  o.w = f2bf(fmaxf(fmaf(p3.x, bf2f(v.w), p3.y), 0.0f));
  ((ushort4*)Xb2)[e] = o;
}

// ---------------------------------------------------------------------------
// 5) final BN + ReLU in place on d_out [B][H][N]; params on the fly.
//    c = (e>>12)&255 is block-uniform -> scalar loads.
// ---------------------------------------------------------------------------
__global__ __launch_bounds__(256) void k_bn_relu(float* __restrict__ out,
                                                 const float* __restrict__ acc2,
                                                 const float* __restrict__ gamma,
                                                 const float* __restrict__ beta) {
  size_t e = (size_t)blockIdx.x * 256 + threadIdx.x;
  float4 v = ((float4*)out)[e];
  int c = (int)((e >> 12) & 255);
  float2 p = bnparam(acc2[c], acc2[256 + c], gamma[c], beta[c]);
  v.x = fmaxf(fmaf(p.x, v.x, p.y), 0.0f);
  v.y = fmaxf(fmaf(p.x, v.y, p.y), 0.0f);
  v.z = fmaxf(fmaf(p.x, v.z, p.y), 0.0f);
  v.w = fmaxf(fmaf(p.x, v.w, p.y), 0.0f);
  ((float4*)out)[e] = v;
}

// ---------------------------------------------------------------------------
extern "C" void kernel_launch(void* const* d_in, const int* in_sizes, int n_in,
                              void* d_out, int out_size, void* d_ws, size_t ws_size,
                              hipStream_t stream) {
  const float* unknown = (const float*)d_in[0];
  const float* known   = (const float*)d_in[1];
  const float* uf      = (const float*)d_in[2];
  const float* kf      = (const float*)d_in[3];
  const float* W1      = (const float*)d_in[4];
  const float* g1      = (const float*)d_in[5];
  const float* b1      = (const float*)d_in[6];
  const float* W2      = (const float*)d_in[7];
  const float* g2      = (const float*)d_in[8];
  const float* b2      = (const float*)d_in[9];
  float* out = (float*)d_out;

  // workspace: kfT 16.8MB | Xb1 48MB (alias Xb2 late) | Wb 0.33MB | acc 4KB
  // d_out (64MB) scratch timeline: part_d/part_i (12.6MB, k_front -> pre2)
  //   -> h bf16 (32MB, GEMM1 -> bn_relu_cast) -> final out fp32 (GEMM2+).
  float* ws = (float*)d_ws;
  float*          kfT  = ws;
  unsigned short* Xb1  = (unsigned short*)(kfT + (size_t)B_*M_*C2_);
  unsigned short* Xb2  = Xb1;                                         // alias (late)
  unsigned short* W1b  = Xb1 + (size_t)B_*N_*K1_;
  unsigned short* W2b  = W1b + H_*K1_;
  float* acc1   = (float*)(W2b + H_*H_);       // [0:256) sum, [256:512) sumsq
  float* acc2   = acc1 + 512;
  float* part_d = out;                                                // d_out scratch
  int*   part_i = (int*)(part_d + (size_t)NC_*B_*3*N_);
  float* h      = out;                                                // d_out scratch (bf16)

  k_front<<<4736 + 2048, 256, 0, stream>>>(kf, kfT, W1, W2, W1b,
                                           unknown, known, part_d, part_i);
  k_pre2<<<dim3(N_/32, 5, B_), 256, 0, stream>>>(part_d, part_i, kfT, uf, Xb1, acc1);
  k_gemm_mfma<K1_, 0><<<dim3(N_/128, 2, B_), 256, 0, stream>>>(W1b, Xb1, h, acc1);
  k_bn_relu_cast<<<(int)((size_t)B_*N_*H_/4/256), 256, 0, stream>>>((unsigned short*)h, acc1, g1, b1, Xb2, acc2);
  k_gemm_mfma<H_, 1><<<dim3(N_/128, 2, B_), 256, 0, stream>>>(W2b, Xb2, out, acc2);
  k_bn_relu<<<(int)((size_t)B_*H_*N_/4/256), 256, 0, stream>>>(out, acc2, g2, b2);
}

// Round 11
// 344.436 us; speedup vs baseline: 1.0005x; 1.0005x over previous
//
#include <hip/hip_runtime.h>
#include <math.h>

// Shapes (fixed by the problem)
#define B_   4
#define N_   16384
#define M_   4096
#define C1_  128
#define C2_  256
#define H_   256
#define K1_  384   // C1 + C2

#define NC_  8           // three_nn chunks over M  (DO NOT CHANGE: selection
#define MC_  (M_ / NC_)  //  dynamics are part of the verified numerics)

typedef unsigned long long u64;
typedef __attribute__((ext_vector_type(8))) short bf16x8;   // 8 bf16 (4 VGPRs)
typedef __attribute__((ext_vector_type(4))) float f32x4;    // mfma acc

typedef const __attribute__((address_space(1))) unsigned int* gptr_t;
typedef __attribute__((address_space(3))) unsigned int* lptr_t;

__device__ __forceinline__ unsigned short f2bf(float x) {
  unsigned u = __float_as_uint(x);
  return (unsigned short)((u + 0x7FFFu + ((u >> 16) & 1u)) >> 16);  // RNE
}
__device__ __forceinline__ float bf2f(unsigned short u) {
  return __uint_as_float((unsigned)u << 16);
}

// BN scale/shift from raw sums — VERBATIM k_reduce_bn arithmetic.
__device__ __forceinline__ float2 bnparam(float s, float q, float gm, float bt) {
  const float inv = 1.0f / (float)(B_ * N_);
  float mean = s * inv;
  float var  = q * inv - mean * mean;
  float sc = gm / sqrtf(var + 1e-5f);
  return make_float2(sc, bt - mean * sc);
}

// fp32-pair branchless insert (merge phase only)
__device__ __forceinline__ void ins3(float cd, int ci,
                                     float& d1, int& i1,
                                     float& d2, int& i2,
                                     float& d3, int& i3) {
  bool p3 = cd < d3, p2 = cd < d2, p1 = cd < d1;
  float td = p1 ? d1 : cd; int ti = p1 ? i1 : ci;
  d1 = p1 ? cd : d1;       i1 = p1 ? ci : i1;
  float e3 = p2 ? d2 : cd; int e3i = p2 ? i2 : ci;
  d2 = p2 ? td : d2;       i2 = p2 ? ti : i2;
  d3 = p3 ? e3 : d3;       i3 = p3 ? e3i : i3;
}

// ---------------------------------------------------------------------------
// 1) k_front — flat grid fusing three independent jobs:
//      f in [0,4096)     : transpose known_feats -> kfT        (short, first)
//      f in [4096,4736)  : cast W1/W2 -> bf16 Wb               (short)
//      f in [4736,6784)  : three_nn partials                   (long, backfills)
//    three_nn decode g=f-4736: x=g&63, b=(g>>6)&3, ch=g>>8 == the verified
//    dim3(64,4,8) x-fastest mapping -> block->(j,b,ch) and wave composition
//    BYTE-IDENTICAL -> selection dynamics unchanged (R4-proven numerics).
// ---------------------------------------------------------------------------
__global__ __launch_bounds__(256) void k_front(const float* __restrict__ kf,
                                               float* __restrict__ kfT,
                                               const float* __restrict__ W1,
                                               const float* __restrict__ W2,
                                               unsigned short* __restrict__ Wb,
                                               const float* __restrict__ unknown,
                                               const float* __restrict__ known,
                                               float* __restrict__ part_d,
                                               int* __restrict__ part_i) {
  __shared__ __align__(16) char smem[8192];
  int f = blockIdx.x;
  int t = threadIdx.x;

  if (f < 4096) {              // ---- transpose kf [B,C2,M] -> kfT [B,M,C2]
    float (*tile)[33] = (float (*)[33])smem;
    int b  = f >> 10;
    int c0 = ((f >> 7) & 7) * 32;
    int i0 = (f & 127) * 32;
    int tx = t & 31, tyv = t >> 5;
    const float* src = kf + ((size_t)b * C2_ + c0) * M_ + i0;
    #pragma unroll
    for (int r = 0; r < 32; r += 8)
      tile[tyv + r][tx] = src[(size_t)(tyv + r) * M_ + tx];
    __syncthreads();
    float* dst = kfT + ((size_t)b * M_ + i0) * C2_ + c0;
    #pragma unroll
    for (int r = 0; r < 32; r += 8)
      dst[(size_t)(tyv + r) * C2_ + tx] = tile[tx][tyv + r];
    return;
  }
  if (f < 4736) {              // ---- wcast
    int i = (f - 4096) * 256 + t;
    int n1 = H_ * K1_, nt = n1 + H_ * H_;
    if (i < nt) Wb[i] = f2bf(i < n1 ? W1[i] : W2[i - n1]);
    return;
  }

  // ---- three_nn partials — BYTE-EXACT R4 body (DO NOT TOUCH) ----
  float4* sk = (float4*)smem;
  int g    = f - 4736;
  int b    = (g >> 6) & 3;
  int ch   = g >> 8;
  int base = ch * MC_;
  const float* kb = known + ((size_t)b * M_ + base) * 3;
  for (int i = t; i < MC_; i += 256) {
    float x = kb[3*i+0], y = kb[3*i+1], z = kb[3*i+2];
    sk[i] = make_float4(-2.0f*x, -2.0f*y, -2.0f*z, x*x + y*y + z*z);
  }
  __syncthreads();

  int j = (g & 63) * 256 + t;
  const float* up = unknown + ((size_t)b * N_ + j) * 3;
  float ux = up[0], uy = up[1], uz = up[2];
  float u2 = ux*ux + uy*uy + uz*uz;

  const float INF = __builtin_inff();
  float d1 = INF, d2 = INF, d3 = INF, t3 = INF;
  int   i1 = 0, i2 = 0, i3 = 0;
  #pragma unroll 4
  for (int i = 0; i < MC_; ++i) {
    float4 k = sk[i];
    float s = fmaf(k.x, ux, fmaf(k.y, uy, fmaf(k.z, uz, k.w)));  // k2 - 2*dot
    if (__any(s < t3)) {
      float d = u2 + s;
      int  gi = base + i;
      bool p3 = d < d3, p2 = d < d2, p1 = d < d1;
      int ni1 = p1 ? gi : i1;
      int ni2 = p1 ? i1 : (p2 ? gi : i2);
      int ni3 = p2 ? i2 : (p3 ? gi : i3);
      float nd1 = fminf(d, d1);
      float nd2 = __builtin_amdgcn_fmed3f(d, d1, d2);
      float nd3 = __builtin_amdgcn_fmed3f(d, d2, d3);
      d1 = nd1; d2 = nd2; d3 = nd3;
      i1 = ni1; i2 = ni2; i3 = ni3;
      t3 = d3 - u2;
    }
  }
  size_t o = ((size_t)(ch * B_ + b) * 3) * N_ + j;
  part_d[o] = d1; part_d[o + N_] = d2; part_d[o + 2*(size_t)N_] = d3;
  part_i[o] = i1; part_i[o + N_] = i2; part_i[o + 2*(size_t)N_] = i3;
}

// ---------------------------------------------------------------------------
// 2) pre2: fused {merge + three_interpolate} (y==4) and uf_t (y<4).
//    Bodies verbatim (bit-identical Xb1). The (x==0,y==4,b==0) block also
//    zeroes the layer-1 BN accumulators for this iteration.
// ---------------------------------------------------------------------------
__global__ __launch_bounds__(256) void k_pre2(const float* __restrict__ part_d,
                                              const int* __restrict__ part_i,
                                              const float* __restrict__ kfT,
                                              const float* __restrict__ uf,
                                              unsigned short* __restrict__ Xb1,
                                              float* __restrict__ acc1) {
  int b = blockIdx.z;
  if (blockIdx.y < 4) {
    // ---- uf_t: transpose+cast unknown_feats [B,C1,N] -> Xb1[b][j][256+c]
    __shared__ float tile[32][33];
    int j0 = blockIdx.x * 32;
    int c0 = blockIdx.y * 32;
    int tx = threadIdx.x & 31, ty = threadIdx.x >> 5;
    const float* src = uf + ((size_t)b * C1_ + c0) * N_ + j0;
    #pragma unroll
    for (int r = 0; r < 32; r += 8)
      tile[ty + r][tx] = src[(size_t)(ty + r) * N_ + tx];
    __syncthreads();
    unsigned short* dst = Xb1 + ((size_t)b * N_ + j0) * K1_ + C2_ + c0;
    #pragma unroll
    for (int r = 0; r < 32; r += 8)
      dst[(size_t)(ty + r) * K1_ + tx] = f2bf(tile[tx][ty + r]);
    return;
  }
  int t  = threadIdx.x;
  if (blockIdx.x == 0 && b == 0) {      // zero layer-1 BN accumulators
    acc1[t] = 0.0f; acc1[256 + t] = 0.0f;
  }
  // ---- merge (threads 0..31, one point each) + interp (all 256 threads)
  __shared__ float lw[32][3];
  __shared__ int   li[32][3];
  int j0 = blockIdx.x * 32;
  if (t < 32) {
    int j = j0 + t;
    size_t o0 = ((size_t)b * 3) * N_ + j;
    float d1 = part_d[o0], d2 = part_d[o0 + N_], d3 = part_d[o0 + 2*(size_t)N_];
    int   i1 = part_i[o0], i2 = part_i[o0 + N_], i3 = part_i[o0 + 2*(size_t)N_];
    #pragma unroll
    for (int c = 1; c < NC_; ++c) {
      size_t oc = ((size_t)(c * B_ + b) * 3) * N_ + j;
      #pragma unroll
      for (int k = 0; k < 3; ++k) {
        float cd = part_d[oc + (size_t)k * N_];
        int   ci = part_i[oc + (size_t)k * N_];
        ins3(cd, ci, d1, i1, d2, i2, d3, i3);
      }
    }
    float r1 = 1.0f / (d1 + 1e-8f);
    float r2 = 1.0f / (d2 + 1e-8f);
    float r3 = 1.0f / (d3 + 1e-8f);
    float s  = r1 + r2 + r3;
    li[t][0] = i1; li[t][1] = i2; li[t][2] = i3;
    lw[t][0] = r1 / s; lw[t][1] = r2 / s; lw[t][2] = r3 / s;
  }
  __syncthreads();
  const float* kb = kfT + (size_t)b * M_ * C2_;
  int c = t;
  for (int p = 0; p < 32; ++p) {
    int   i0 = li[p][0], i1 = li[p][1], i2 = li[p][2];
    float w0 = lw[p][0], w1 = lw[p][1], w2 = lw[p][2];
    float v = w0 * kb[(size_t)i0 * C2_ + c]
            + w1 * kb[(size_t)i1 * C2_ + c]
            + w2 * kb[(size_t)i2 * C2_ + c];
    Xb1[((size_t)b * N_ + j0 + p) * K1_ + c] = f2bf(v);
  }
}

// ---------------------------------------------------------------------------
// 3) bf16 MFMA GEMM — DOUBLE-BUFFERED LDS stage-ahead K-loop.
//    Old loop: STAGE -> sync -> compute -> sync  (every step pays the full
//    ~900cy global_load_lds latency serially before compute).
//    New loop: STAGE(next into buf^1) -> compute(buf) -> __syncthreads().
//    The load flight overlaps compute; __syncthreads' built-in
//    vmcnt(0)+lgkmcnt(0) drain provides all ordering (next-buffer writes
//    landed before anyone reads them; all ds_reads of the buffer STAGE will
//    overwrite next iteration are complete). One barrier/step instead of
//    two; latency exposed only at the prologue. Plain HIP, no inline asm.
//    Operand values, MFMA order, stats path, stores: byte-identical to the
//    verified R9/R10 kernel -> output bits unchanged.
// ---------------------------------------------------------------------------
template <int K, int OUTL>
__global__ __launch_bounds__(256) void k_gemm_mfma(const unsigned short* __restrict__ Wb,
                                                   const unsigned short* __restrict__ Xb,
                                                   float* __restrict__ outp,
                                                   float* __restrict__ acc) {
  __shared__ float sred[256];
  __shared__ unsigned short lA[2][4096];   // 2 x [128][32] bf16 = 16 KB
  __shared__ unsigned short lB[2][4096];
  int t = threadIdx.x;
  sred[t] = 0.0f;

  int b  = blockIdx.z;
  int m0 = blockIdx.y * 128;
  int j0 = blockIdx.x * 128;
  int wid = t >> 6, lane = t & 63;
  int wr = wid >> 1, wc = wid & 1;
  int l15 = lane & 15, quad = lane >> 4;

  int srow = lane >> 2;
  int scol = (lane & 3) * 8;
  int c0 = wid * 2, c1 = wid * 2 + 1;
  const unsigned short* gA0 = Wb + (size_t)(m0 + c0*16 + srow) * K + scol;
  const unsigned short* gA1 = Wb + (size_t)(m0 + c1*16 + srow) * K + scol;
  const unsigned short* gB0 = Xb + ((size_t)b * N_ + j0 + c0*16 + srow) * K + scol;
  const unsigned short* gB1 = Xb + ((size_t)b * N_ + j0 + c1*16 + srow) * K + scol;

  // stage K-step kt into buffer bf
  auto STAGE = [&](int bf, int kt) {
    __builtin_amdgcn_global_load_lds((gptr_t)(gA0 + kt), (lptr_t)(lA[bf] + c0 * 512), 16, 0, 0);
    __builtin_amdgcn_global_load_lds((gptr_t)(gA1 + kt), (lptr_t)(lA[bf] + c1 * 512), 16, 0, 0);
    __builtin_amdgcn_global_load_lds((gptr_t)(gB0 + kt), (lptr_t)(lB[bf] + c0 * 512), 16, 0, 0);
    __builtin_amdgcn_global_load_lds((gptr_t)(gB1 + kt), (lptr_t)(lB[bf] + c1 * 512), 16, 0, 0);
  };

  int fA = (64*wr + l15) * 32 + quad * 8;
  int fB = (64*wc + l15) * 32 + quad * 8;

  STAGE(0, 0);
  __syncthreads();                 // drains vmcnt(0): buf0 ready; sred zeroed

  f32x4 acc_r[4][4] = {};
  int buf = 0;
  for (int kt = 0; kt < K; kt += 32) {
    if (kt + 32 < K) STAGE(buf ^ 1, kt + 32);   // prefetch next K-step
    bf16x8 af[4], bfr[4];
    #pragma unroll
    for (int i = 0; i < 4; ++i)
      af[i] = *(const bf16x8*)(lA[buf] + fA + i * 512);
    #pragma unroll
    for (int i = 0; i < 4; ++i)
      bfr[i] = *(const bf16x8*)(lB[buf] + fB + i * 512);
    #pragma unroll
    for (int im = 0; im < 4; ++im)
      #pragma unroll
      for (int in = 0; in < 4; ++in)
        acc_r[im][in] = __builtin_amdgcn_mfma_f32_16x16x32_bf16(af[im], bfr[in], acc_r[im][in], 0, 0, 0);
    __syncthreads();               // drains vmcnt+lgkm: next buf ready, cur buf free
    buf ^= 1;
  }

  // --- BN statistics: shuffle-reduce over 16 n-lanes, combine in LDS ---
  #pragma unroll
  for (int im = 0; im < 4; ++im) {
    #pragma unroll
    for (int r = 0; r < 4; ++r) {
      float sv = 0.f, qv = 0.f;
      #pragma unroll
      for (int in = 0; in < 4; ++in) { float v = acc_r[im][in][r]; sv += v; qv += v * v; }
      #pragma unroll
      for (int off = 1; off < 16; off <<= 1) {
        sv += __shfl_xor(sv, off, 64);
        qv += __shfl_xor(qv, off, 64);
      }
      if (l15 == 0) {
        int ml = 64*wr + 16*im + 4*quad + r;
        atomicAdd(&sred[ml], sv);
        atomicAdd(&sred[128 + ml], qv);
      }
    }
  }
  __syncthreads();
  if (t < 128) {
    atomicAdd(&acc[m0 + t],       sred[t]);        // device-scope fp32 atomics
    atomicAdd(&acc[256 + m0 + t], sred[128 + t]);
  }

  // --- store ---
  if (OUTL == 0) {
    unsigned short* hp = (unsigned short*)outp;   // h bf16 [b][n][256]
    #pragma unroll
    for (int in = 0; in < 4; ++in) {
      size_t nrow = (size_t)b * N_ + j0 + 64*wc + 16*in + l15;
      unsigned short* p = hp + nrow * 256 + m0 + 64*wr + quad * 4;
      #pragma unroll
      for (int im = 0; im < 4; ++im) {
        ushort4 o;
        o.x = f2bf(acc_r[im][in][0]); o.y = f2bf(acc_r[im][in][1]);
        o.z = f2bf(acc_r[im][in][2]); o.w = f2bf(acc_r[im][in][3]);
        *(ushort4*)(p + 16 * im) = o;
      }
    }
  } else {
    #pragma unroll
    for (int im = 0; im < 4; ++im)
      #pragma unroll
      for (int r = 0; r < 4; ++r) {
        int m = m0 + 64*wr + 16*im + 4*quad + r;
        size_t base = ((size_t)b * 256 + m) * N_ + j0 + 64*wc + l15;
        #pragma unroll
        for (int in = 0; in < 4; ++in)
          outp[base + 16 * in] = acc_r[im][in][r];
      }
  }
}

// ---------------------------------------------------------------------------
// 4) bn1 + relu: h bf16 -> Xb2 bf16. BN params computed on the fly from the
//    raw atomic sums (formula verbatim == old reduce_bn). Block 0 zeroes the
//    layer-2 accumulators for gemm2.
// ---------------------------------------------------------------------------
__global__ __launch_bounds__(256) void k_bn_relu_cast(const unsigned short* __restrict__ h,
                                                      const float* __restrict__ acc1,
                                                      const float* __restrict__ gamma,
                                                      const float* __restrict__ beta,
                                                      unsigned short* __restrict__ Xb2,
                                                      float* __restrict__ acc2) {
  int t = threadIdx.x;
  if (blockIdx.x == 0) { acc2[t] = 0.0f; acc2[256 + t] = 0.0f; }
  size_t e = (size_t)blockIdx.x * 256 + t;             // ushort4 index
  ushort4 v = ((const ushort4*)h)[e];
  int c0 = (int)((e & 63) << 2);
  float4 s4 = *(const float4*)(acc1 + c0);
  float4 q4 = *(const float4*)(acc1 + 256 + c0);
  float4 gm = *(const float4*)(gamma + c0);
  float4 bt = *(const float4*)(beta + c0);
  float2 p0 = bnparam(s4.x, q4.x, gm.x, bt.x);
  float2 p1 = bnparam(s4.y, q4.y, gm.y, bt.y);
  float2 p2 = bnparam(s4.z, q4.z, gm.z, bt.z);
  float2 p3 = bnparam(s4.w, q4.w, gm.w, bt.w);
  ushort4 o;
  o.x = f2bf(fmaxf(fmaf(p0.x, bf2f(v.x), p0.y), 0.0f));
  o.y = f2bf(fmaxf(fmaf(p1.x, bf2f(v.y), p1.y), 0.0f));
  o.z = f2bf(fmaxf(fmaf(p2.x, bf2f(v.z), p2.y), 0.0f));
  o.w = f2bf(fmaxf(fmaf(p3.x, bf2f(v.w), p3.y), 0.0f));
  ((ushort4*)Xb2)[e] = o;
}

// ---------------------------------------------------------------------------
// 5) final BN + ReLU in place on d_out [B][H][N]; params on the fly.
//    c = (e>>12)&255 is block-uniform -> scalar loads.
// ---------------------------------------------------------------------------
__global__ __launch_bounds__(256) void k_bn_relu(float* __restrict__ out,
                                                 const float* __restrict__ acc2,
                                                 const float* __restrict__ gamma,
                                                 const float* __restrict__ beta) {
  size_t e = (size_t)blockIdx.x * 256 + threadIdx.x;
  float4 v = ((float4*)out)[e];
  int c = (int)((e >> 12) & 255);
  float2 p = bnparam(acc2[c], acc2[256 + c], gamma[c], beta[c]);
  v.x = fmaxf(fmaf(p.x, v.x, p.y), 0.0f);
  v.y = fmaxf(fmaf(p.x, v.y, p.y), 0.0f);
  v.z = fmaxf(fmaf(p.x, v.z, p.y), 0.0f);
  v.w = fmaxf(fmaf(p.x, v.w, p.y), 0.0f);
  ((float4*)out)[e] = v;
}

// ---------------------------------------------------------------------------
extern "C" void kernel_launch(void* const* d_in, const int* in_sizes, int n_in,
                              void* d_out, int out_size, void* d_ws, size_t ws_size,
                              hipStream_t stream) {
  const float* unknown = (const float*)d_in[0];
  const float* known   = (const float*)d_in[1];
  const float* uf      = (const float*)d_in[2];
  const float* kf      = (const float*)d_in[3];
  const float* W1      = (const float*)d_in[4];
  const float* g1      = (const float*)d_in[5];
  const float* b1      = (const float*)d_in[6];
  const float* W2      = (const float*)d_in[7];
  const float* g2      = (const float*)d_in[8];
  const float* b2      = (const float*)d_in[9];
  float* out = (float*)d_out;

  // workspace: kfT 16.8MB | Xb1 48MB (alias Xb2 late) | Wb 0.33MB | acc 4KB
  // d_out (64MB) scratch timeline: part_d/part_i (12.6MB, k_front -> pre2)
  //   -> h bf16 (32MB, GEMM1 -> bn_relu_cast) -> final out fp32 (GEMM2+).
  float* ws = (float*)d_ws;
  float*          kfT  = ws;
  unsigned short* Xb1  = (unsigned short*)(kfT + (size_t)B_*M_*C2_);
  unsigned short* Xb2  = Xb1;                                         // alias (late)
  unsigned short* W1b  = Xb1 + (size_t)B_*N_*K1_;
  unsigned short* W2b  = W1b + H_*K1_;
  float* acc1   = (float*)(W2b + H_*H_);       // [0:256) sum, [256:512) sumsq
  float* acc2   = acc1 + 512;
  float* part_d = out;                                                // d_out scratch
  int*   part_i = (int*)(part_d + (size_t)NC_*B_*3*N_);
  float* h      = out;                                                // d_out scratch (bf16)

  k_front<<<4736 + 2048, 256, 0, stream>>>(kf, kfT, W1, W2, W1b,
                                           unknown, known, part_d, part_i);
  k_pre2<<<dim3(N_/32, 5, B_), 256, 0, stream>>>(part_d, part_i, kfT, uf, Xb1, acc1);
  k_gemm_mfma<K1_, 0><<<dim3(N_/128, 2, B_), 256, 0, stream>>>(W1b, Xb1, h, acc1);
  k_bn_relu_cast<<<(int)((size_t)B_*N_*H_/4/256), 256, 0, stream>>>((unsigned short*)h, acc1, g1, b1, Xb2, acc2);
  k_gemm_mfma<H_, 1><<<dim3(N_/128, 2, B_), 256, 0, stream>>>(W2b, Xb2, out, acc2);
  k_bn_relu<<<(int)((size_t)B_*H_*N_/4/256), 256, 0, stream>>>(out, acc2, g2, b2);
}